// Round 1
// baseline (434.291 us; speedup 1.0000x reference)
//
#include <hip/hip_runtime.h>
#include <hip/hip_bf16.h>

typedef unsigned short u16;
typedef unsigned int   u32;
typedef __attribute__((ext_vector_type(8))) short  s16x8;
typedef __attribute__((ext_vector_type(4))) float  f32x4;
typedef __attribute__((ext_vector_type(4))) unsigned short u16x4;

#define MT    8192   // B*S tokens
#define DE    2048   // embed dim
#define NEXP  64     // experts
#define ERDIM 4096   // experts * rank

// round-to-nearest-even f32 -> bf16
__device__ __forceinline__ u16 to_bf16(float f) {
  u32 u = __builtin_bit_cast(u32, f);
  u32 r = u + 0x7fffu + ((u >> 16) & 1u);
  return (u16)(r >> 16);
}

__global__ void cvt_f32_bf16(const float* __restrict__ in, u16* __restrict__ out, int n) {
  const int stride = gridDim.x * blockDim.x;
  for (int i = blockIdx.x * blockDim.x + threadIdx.x; i * 4 < n; i += stride) {
    const float4 v = *reinterpret_cast<const float4*>(in + (size_t)i * 4);
    u16x4 o;
    o.x = to_bf16(v.x); o.y = to_bf16(v.y); o.z = to_bf16(v.z); o.w = to_bf16(v.w);
    *reinterpret_cast<u16x4*>(out + (size_t)i * 4) = o;
  }
}

#define GLDS(gp, lp) __builtin_amdgcn_global_load_lds(                        \
    (const __attribute__((address_space(1))) void*)(gp),                      \
    (__attribute__((address_space(3))) void*)(lp), 16, 0, 0)

// C = A[M,K] * B[N,K]^T  (both bf16, row-major, K contiguous)
// FUSE=1: C_bf16[m,n] = bf16( silu(acc) * mask[m, n>>6] )
// FUSE=0: C_f32[m,n]  = acc
template<int FUSE>
__global__ __launch_bounds__(256) void gemm_bt(
    const u16* __restrict__ A, const u16* __restrict__ Bmat,
    const float* __restrict__ mask, void* __restrict__ Cout,
    const int M, const int N, const int K)
{
  constexpr int BM = 128, BN = 128, BK = 32;
  __shared__ u16 lA[BM * BK];   // 8 KiB
  __shared__ u16 lB[BN * BK];   // 8 KiB

  const int nbn = N / BN;
  const int nwg = (int)gridDim.x;
  const int cpx = nwg >> 3;                       // nwg % 8 == 0 guaranteed
  const int bid = (int)blockIdx.x;
  const int swz = (bid & 7) * cpx + (bid >> 3);   // bijective XCD swizzle
  const int bm = (swz / nbn) * BM;
  const int bn = (swz % nbn) * BN;

  const int tid  = (int)threadIdx.x;
  const int lane = tid & 63;
  const int w    = tid >> 6;          // wave 0..3
  const int wm   = (w >> 1) * 64;     // wave sub-tile origin
  const int wn   = (w & 1) * 64;

  // staging geometry: tile is 128 rows x 64 bytes, waves write linear 1KiB chunks
  const int b0 = w * 1024 + lane * 16;  // byte offset, round 0
  const int r0 = b0 >> 6;               // row
  const int c0 = (b0 & 63) >> 1;        // element col within BK
  const int r1 = r0 + 64;               // round 1 (+4096B)

  const u16* Ag0 = A    + (size_t)(bm + r0) * K + c0;
  const u16* Ag1 = A    + (size_t)(bm + r1) * K + c0;
  const u16* Bg0 = Bmat + (size_t)(bn + r0) * K + c0;
  const u16* Bg1 = Bmat + (size_t)(bn + r1) * K + c0;

  u16* lAw = lA + w * 512;  // wave-uniform LDS chunk base (1 KiB per wave)
  u16* lBw = lB + w * 512;

  const int fr = lane & 15;
  const int kg = (lane >> 4) * 8;

  f32x4 acc[4][4] = {};

  for (int k0 = 0; k0 < K; k0 += BK) {
    GLDS(Ag0 + k0, lAw);
    GLDS(Ag1 + k0, lAw + 2048);
    GLDS(Bg0 + k0, lBw);
    GLDS(Bg1 + k0, lBw + 2048);
    __syncthreads();   // compiler emits vmcnt(0) drain before barrier

    s16x8 af[4], bf[4];
#pragma unroll
    for (int m = 0; m < 4; ++m)
      af[m] = *reinterpret_cast<const s16x8*>(&lA[(wm + m * 16 + fr) * BK + kg]);
#pragma unroll
    for (int n = 0; n < 4; ++n)
      bf[n] = *reinterpret_cast<const s16x8*>(&lB[(wn + n * 16 + fr) * BK + kg]);
#pragma unroll
    for (int m = 0; m < 4; ++m)
#pragma unroll
      for (int n = 0; n < 4; ++n)
        acc[m][n] = __builtin_amdgcn_mfma_f32_16x16x32_bf16(af[m], bf[n], acc[m][n], 0, 0, 0);
    __syncthreads();
  }

  // epilogue: C/D layout col=lane&15, row=(lane>>4)*4 + j  [m89-verified]
  const int rgrp = (lane >> 4) * 4;
#pragma unroll
  for (int m = 0; m < 4; ++m) {
#pragma unroll
    for (int n = 0; n < 4; ++n) {
      const int gcol = bn + wn + n * 16 + fr;
      const int e = gcol >> 6;  // expert id (fragment-uniform: tiles are 16-aligned in 64-wide experts)
#pragma unroll
      for (int j = 0; j < 4; ++j) {
        const int grow = bm + wm + m * 16 + rgrp + j;
        float v = acc[m][n][j];
        if (FUSE) {
          v = v / (1.0f + __expf(-v));         // silu
          v *= mask[(size_t)grow * NEXP + e];  // expert mask
          ((u16*)Cout)[(size_t)grow * N + gcol] = to_bf16(v);
        } else {
          ((float*)Cout)[(size_t)grow * N + gcol] = v;
        }
      }
    }
  }
}

extern "C" void kernel_launch(void* const* d_in, const int* in_sizes, int n_in,
                              void* d_out, int out_size, void* d_ws, size_t ws_size,
                              hipStream_t stream) {
  const float* x     = (const float*)d_in[0];
  const float* emask = (const float*)d_in[1];
  const float* w_up  = (const float*)d_in[2];
  const float* w_dn  = (const float*)d_in[3];
  float* out = (float*)d_out;

  // workspace layout (bf16): x[8192,2048] | w_up[4096,2048] | w_dn[2048,4096] | H[8192,4096]
  const size_t need = ((size_t)MT * DE + (size_t)ERDIM * DE + (size_t)DE * ERDIM +
                       (size_t)MT * ERDIM) * sizeof(u16);
  if (ws_size < need) return;  // fail visibly rather than corrupt memory

  u16* xb  = (u16*)d_ws;
  u16* wub = xb  + (size_t)MT * DE;
  u16* wdb = wub + (size_t)ERDIM * DE;
  u16* hb  = wdb + (size_t)DE * ERDIM;

  hipLaunchKernelGGL(cvt_f32_bf16, dim3(2048), dim3(256), 0, stream, x,    xb,  MT * DE);
  hipLaunchKernelGGL(cvt_f32_bf16, dim3(1024), dim3(256), 0, stream, w_up, wub, ERDIM * DE);
  hipLaunchKernelGGL(cvt_f32_bf16, dim3(1024), dim3(256), 0, stream, w_dn, wdb, DE * ERDIM);

  // GEMM1: H = silu(X @ Wup^T) * mask   [M=8192, N=4096, K=2048]
  hipLaunchKernelGGL((gemm_bt<1>), dim3((MT / 128) * (ERDIM / 128)), dim3(256), 0, stream,
                     xb, wub, emask, (void*)hb, MT, ERDIM, DE);
  // GEMM2: out = H @ Wdown^T             [M=8192, N=2048, K=4096]
  hipLaunchKernelGGL((gemm_bt<0>), dim3((MT / 128) * (DE / 128)), dim3(256), 0, stream,
                     hb, wdb, nullptr, (void*)out, MT, DE, ERDIM);
}

// Round 2
// 309.930 us; speedup vs baseline: 1.4013x; 1.4013x over previous
//
#include <hip/hip_runtime.h>
#include <hip/hip_bf16.h>

typedef unsigned short u16;
typedef unsigned int   u32;
typedef __attribute__((ext_vector_type(8))) short  s16x8;
typedef __attribute__((ext_vector_type(4))) float  f32x4;
typedef __attribute__((ext_vector_type(4))) unsigned short u16x4;

#define MT    8192   // B*S tokens
#define DE    2048   // embed dim
#define NEXP  64     // experts
#define ERDIM 4096   // experts * rank

// round-to-nearest-even f32 -> bf16
__device__ __forceinline__ u16 to_bf16(float f) {
  u32 u = __builtin_bit_cast(u32, f);
  u32 r = u + 0x7fffu + ((u >> 16) & 1u);
  return (u16)(r >> 16);
}

__global__ void cvt_f32_bf16(const float* __restrict__ in, u16* __restrict__ out, int n) {
  const int stride = gridDim.x * blockDim.x;
  for (int i = blockIdx.x * blockDim.x + threadIdx.x; i * 4 < n; i += stride) {
    const float4 v = *reinterpret_cast<const float4*>(in + (size_t)i * 4);
    u16x4 o;
    o.x = to_bf16(v.x); o.y = to_bf16(v.y); o.z = to_bf16(v.z); o.w = to_bf16(v.w);
    *reinterpret_cast<u16x4*>(out + (size_t)i * 4) = o;
  }
}

#define GLDS(gp, lp) __builtin_amdgcn_global_load_lds(                        \
    (const __attribute__((address_space(1))) void*)(gp),                      \
    (__attribute__((address_space(3))) void*)(lp), 16, 0, 0)

#define BAR() do { asm volatile("" ::: "memory");                             \
                   __builtin_amdgcn_s_barrier();                              \
                   asm volatile("" ::: "memory"); } while (0)

// C = A[M,K] * B[N,K]^T (bf16, row-major). 256x256 tile, BK=32, 8 waves (2Mx4N),
// 4-slot LDS ring (128 KiB), prefetch distance 2, counted vmcnt, setprio MFMA.
// T2 swizzle: linear LDS dest (global_load_lds) + inverse-swizzled global src,
// reads use matching granule-XOR -> conflict-free ds_read_b128.
// FUSE=1: C_bf16[m,n] = bf16( silu(acc) * mask[m, n>>6] );  FUSE=0: C_f32 = acc
template<int FUSE>
__global__ __launch_bounds__(512) void gemm_bt(
    const u16* __restrict__ A, const u16* __restrict__ Bm,
    const float* __restrict__ mask, void* __restrict__ Cout,
    const int M, const int N, const int K)
{
  constexpr int BM = 256, BN = 256, BK = 32;
  // 4 slots x (A 16KB + B 16KB) = 128 KiB
  __shared__ __align__(16) u16 lds[65536];

  const int nbn = N / BN;
  const int nwg = (int)gridDim.x;
  const int cpx = nwg >> 3;                      // nwg % 8 == 0 for all our grids
  const int bid = (int)blockIdx.x;
  const int swz = (bid & 7) * cpx + (bid >> 3);  // bijective XCD swizzle
  const int bm = (swz / nbn) * BM;
  const int bn = (swz % nbn) * BN;

  const int tid  = (int)threadIdx.x;
  const int lane = tid & 63;
  const int w    = tid >> 6;       // wave 0..7
  const int wr   = w >> 2;         // 0..1: M row-group (128 rows)
  const int wc   = w & 3;          // 0..3: N col-group (64 cols)

  const int fr = lane & 15;                          // fragment row
  const int cp = (lane >> 4) ^ ((lane >> 1) & 3);    // swizzled granule col (read)

  // staging: wave w owns chunks {2w, 2w+1} (16 rows x 64B each) of both A and B.
  // per-lane global source is inverse-swizzled so linear LDS holds swizzled data.
  const int lr = lane >> 2;                          // row within chunk
  const int cl = (lane & 3) ^ ((lane >> 3) & 3);     // logical granule col (source)
  const int c0 = 2 * w, c1 = 2 * w + 1;
  const u16* aS0 = A  + (size_t)(bm + c0 * 16 + lr) * K + cl * 8;
  const u16* aS1 = A  + (size_t)(bm + c1 * 16 + lr) * K + cl * 8;
  const u16* bS0 = Bm + (size_t)(bn + c0 * 16 + lr) * K + cl * 8;
  const u16* bS1 = Bm + (size_t)(bn + c1 * 16 + lr) * K + cl * 8;

  const int NT = K / BK;

  f32x4 acc[8][4] = {};

  // ---- prologue: stage tiles 0 and 1 (issue order = consumption order) ----
  GLDS(aS0,      lds + 0 * 16384 +        c0 * 512);
  GLDS(aS1,      lds + 0 * 16384 +        c1 * 512);
  GLDS(bS0,      lds + 0 * 16384 + 8192 + c0 * 512);
  GLDS(bS1,      lds + 0 * 16384 + 8192 + c1 * 512);
  GLDS(aS0 + BK, lds + 1 * 16384 +        c0 * 512);
  GLDS(aS1 + BK, lds + 1 * 16384 +        c1 * 512);
  GLDS(bS0 + BK, lds + 1 * 16384 + 8192 + c0 * 512);
  GLDS(bS1 + BK, lds + 1 * 16384 + 8192 + c1 * 512);
  asm volatile("s_waitcnt vmcnt(4)" ::: "memory");   // tile 0 landed, tile 1 in flight
  BAR();

  // ---- main loop: 2 phases per K-tile, counted vmcnt at tile boundary ----
  for (int t = 0; t < NT; ++t) {
    const int slot = t & 3;
    const u16* sA = lds + slot * 16384;
    const u16* sB = lds + slot * 16384 + 8192;
    const int s2 = (t + 2) & 3;
    u16* dst = lds + s2 * 16384;
    const bool st = (t + 2 < NT);
    const size_t koff = (size_t)(t + 2) * BK;

    s16x8 bfr[4];
#pragma unroll
    for (int mh = 0; mh < 2; ++mh) {
      s16x8 afr[4];
#pragma unroll
      for (int m = 0; m < 4; ++m)
        afr[m] = *reinterpret_cast<const s16x8*>(
            &sA[(wr * 128 + (mh * 4 + m) * 16 + fr) * 32 + cp * 8]);
      if (mh == 0) {
#pragma unroll
        for (int n = 0; n < 4; ++n)
          bfr[n] = *reinterpret_cast<const s16x8*>(
              &sB[(wc * 64 + n * 16 + fr) * 32 + cp * 8]);
        if (st) {
          GLDS(aS0 + koff, dst +        c0 * 512);
          GLDS(aS1 + koff, dst +        c1 * 512);
        }
      } else {
        if (st) {
          GLDS(bS0 + koff, dst + 8192 + c0 * 512);
          GLDS(bS1 + koff, dst + 8192 + c1 * 512);
        }
      }
      BAR();
      __builtin_amdgcn_s_setprio(1);
#pragma unroll
      for (int m = 0; m < 4; ++m)
#pragma unroll
        for (int n = 0; n < 4; ++n)
          acc[mh * 4 + m][n] = __builtin_amdgcn_mfma_f32_16x16x32_bf16(
              afr[m], bfr[n], acc[mh * 4 + m][n], 0, 0, 0);
      __builtin_amdgcn_s_setprio(0);
      if (mh == 0) {
        BAR();
      } else {
        // tile boundary: guarantee tile t+1's staging landed before next reads
        if (t + 2 < NT)      asm volatile("s_waitcnt vmcnt(4)" ::: "memory");
        else if (t + 1 < NT) asm volatile("s_waitcnt vmcnt(0)" ::: "memory");
        if (t + 1 < NT) BAR();
      }
    }
  }

  // ---- epilogue: C/D layout col=lane&15, row=(lane>>4)*4 + j ----
  const int rgrp = (lane >> 4) * 4;
  if (FUSE) {
    u16* H = (u16*)Cout;
    const int ew = (bn + wc * 64) >> 6;  // wave's 64-col span = exactly one expert
#pragma unroll
    for (int m = 0; m < 8; ++m) {
#pragma unroll
      for (int j = 0; j < 4; ++j) {
        const int grow = bm + wr * 128 + m * 16 + rgrp + j;
        const float mv = mask[(size_t)grow * NEXP + ew];
#pragma unroll
        for (int n = 0; n < 4; ++n) {
          const int gcol = bn + wc * 64 + n * 16 + fr;
          float v = acc[m][n][j];
          v = v / (1.0f + __expf(-v));   // silu
          H[(size_t)grow * N + gcol] = to_bf16(v * mv);
        }
      }
    }
  } else {
    float* O = (float*)Cout;
#pragma unroll
    for (int m = 0; m < 8; ++m) {
#pragma unroll
      for (int j = 0; j < 4; ++j) {
        const int grow = bm + wr * 128 + m * 16 + rgrp + j;
#pragma unroll
        for (int n = 0; n < 4; ++n) {
          const int gcol = bn + wc * 64 + n * 16 + fr;
          O[(size_t)grow * N + gcol] = acc[m][n][j];
        }
      }
    }
  }
}

extern "C" void kernel_launch(void* const* d_in, const int* in_sizes, int n_in,
                              void* d_out, int out_size, void* d_ws, size_t ws_size,
                              hipStream_t stream) {
  const float* x     = (const float*)d_in[0];
  const float* emask = (const float*)d_in[1];
  const float* w_up  = (const float*)d_in[2];
  const float* w_dn  = (const float*)d_in[3];
  float* out = (float*)d_out;

  // workspace (bf16): x[8192,2048] | w_up[4096,2048] | w_dn[2048,4096] | H[8192,4096]
  const size_t need = ((size_t)MT * DE + (size_t)ERDIM * DE + (size_t)DE * ERDIM +
                       (size_t)MT * ERDIM) * sizeof(u16);
  if (ws_size < need) return;

  u16* xb  = (u16*)d_ws;
  u16* wub = xb  + (size_t)MT * DE;
  u16* wdb = wub + (size_t)ERDIM * DE;
  u16* hb  = wdb + (size_t)DE * ERDIM;

  hipLaunchKernelGGL(cvt_f32_bf16, dim3(2048), dim3(256), 0, stream, x,    xb,  MT * DE);
  hipLaunchKernelGGL(cvt_f32_bf16, dim3(1024), dim3(256), 0, stream, w_up, wub, ERDIM * DE);
  hipLaunchKernelGGL(cvt_f32_bf16, dim3(1024), dim3(256), 0, stream, w_dn, wdb, DE * ERDIM);

  // GEMM1: H = silu(X @ Wup^T) * mask   [M=8192, N=4096, K=2048] -> 512 blocks
  hipLaunchKernelGGL((gemm_bt<1>), dim3((MT / 256) * (ERDIM / 256)), dim3(512), 0, stream,
                     xb, wub, emask, (void*)hb, MT, ERDIM, DE);
  // GEMM2: out = H @ Wdown^T             [M=8192, N=2048, K=4096] -> 256 blocks
  hipLaunchKernelGGL((gemm_bt<0>), dim3((MT / 256) * (DE / 256)), dim3(512), 0, stream,
                     hb, wdb, nullptr, (void*)out, MT, DE, ERDIM);
}

// Round 3
// 281.793 us; speedup vs baseline: 1.5412x; 1.0998x over previous
//
#include <hip/hip_runtime.h>
#include <hip/hip_bf16.h>

typedef unsigned short u16;
typedef unsigned int   u32;
typedef __attribute__((ext_vector_type(8))) short  s16x8;
typedef __attribute__((ext_vector_type(4))) float  f32x4;
typedef __attribute__((ext_vector_type(4))) unsigned short u16x4;

#define MT    8192   // B*S tokens
#define DE    2048   // embed dim
#define NEXP  64     // experts
#define ERDIM 4096   // experts * rank

// round-to-nearest-even f32 -> bf16
__device__ __forceinline__ u16 to_bf16(float f) {
  u32 u = __builtin_bit_cast(u32, f);
  u32 r = u + 0x7fffu + ((u >> 16) & 1u);
  return (u16)(r >> 16);
}

__global__ void cvt_f32_bf16(const float* __restrict__ in, u16* __restrict__ out, int n) {
  const int stride = gridDim.x * blockDim.x;
  for (int i = blockIdx.x * blockDim.x + threadIdx.x; i * 4 < n; i += stride) {
    const float4 v = *reinterpret_cast<const float4*>(in + (size_t)i * 4);
    u16x4 o;
    o.x = to_bf16(v.x); o.y = to_bf16(v.y); o.z = to_bf16(v.z); o.w = to_bf16(v.w);
    *reinterpret_cast<u16x4*>(out + (size_t)i * 4) = o;
  }
}

#define GLDS(gp, lp) __builtin_amdgcn_global_load_lds(                        \
    (const __attribute__((address_space(1))) void*)(gp),                      \
    (__attribute__((address_space(3))) void*)(lp), 16, 0, 0)

#define BAR() do { asm volatile("" ::: "memory");                             \
                   __builtin_amdgcn_s_barrier();                              \
                   asm volatile("" ::: "memory"); } while (0)

// C = A[M,K] * B[N,K]^T (bf16, row-major). 256x256 tile, BK=32, 8 waves (2Mx4N).
// 4-slot LDS ring (128 KiB), prefetch distance 3, counted vmcnt(8), ONE barrier
// per K-tile (free-running waves per m114 implicit overlap; no pacing barriers).
// T2: linear LDS dest (global_load_lds) + inverse-swizzled global src; reads use
// matching granule-XOR -> conflict-free ds_read_b128 (verified: conflicts == 0).
// FUSE=1: C_bf16[m,n] = bf16( silu(acc) * mask[m, n>>6] );  FUSE=0: C_f32 = acc
template<int FUSE, int K>
__global__ __launch_bounds__(512, 2) void gemm_bt(
    const u16* __restrict__ A, const u16* __restrict__ Bm,
    const float* __restrict__ mask, void* __restrict__ Cout,
    const int M, const int N)
{
  constexpr int BM = 256, BN = 256, BK = 32;
  constexpr int NT = K / BK;
  // 4 slots x (A 8KB + B 8KB) = 64 Kelem = 128 KiB
  __shared__ __align__(16) u16 lds[65536];

  const int nbn = N / BN;
  const int nwg = (int)gridDim.x;
  const int cpx = nwg >> 3;                      // nwg % 8 == 0 for all our grids
  const int bid = (int)blockIdx.x;
  const int swz = (bid & 7) * cpx + (bid >> 3);  // bijective XCD swizzle
  const int bm = (swz / nbn) * BM;
  const int bn = (swz % nbn) * BN;

  const int tid  = (int)threadIdx.x;
  const int lane = tid & 63;
  const int w    = tid >> 6;       // wave 0..7
  const int wr   = w >> 2;         // 0..1: M row-group (128 rows)
  const int wc   = w & 3;          // 0..3: N col-group (64 cols)

  const int fr = lane & 15;                          // fragment row
  const int cp = (lane >> 4) ^ ((lane >> 1) & 3);    // swizzled granule col (read)

  // staging: wave w owns chunks {2w, 2w+1} (16 rows x 64B each) of both A and B.
  // per-lane global source is inverse-swizzled so linear LDS holds swizzled data.
  const int lr = lane >> 2;                          // row within chunk
  const int cl = (lane & 3) ^ ((lane >> 3) & 3);     // logical granule col (source)
  const int c0 = 2 * w, c1 = 2 * w + 1;
  const u16* aS0 = A  + (size_t)(bm + c0 * 16 + lr) * K + cl * 8;
  const u16* aS1 = A  + (size_t)(bm + c1 * 16 + lr) * K + cl * 8;
  const u16* bS0 = Bm + (size_t)(bn + c0 * 16 + lr) * K + cl * 8;
  const u16* bS1 = Bm + (size_t)(bn + c1 * 16 + lr) * K + cl * 8;

  f32x4 acc[8][4] = {};

  // ---- prologue: stage tiles 0,1,2 (issue order = consumption order) ----
#pragma unroll
  for (int t = 0; t < 3; ++t) {
    u16* dst = lds + t * 16384;
    GLDS(aS0 + t * BK, dst +        c0 * 512);
    GLDS(aS1 + t * BK, dst +        c1 * 512);
    GLDS(bS0 + t * BK, dst + 8192 + c0 * 512);
    GLDS(bS1 + t * BK, dst + 8192 + c1 * 512);
  }
  asm volatile("s_waitcnt vmcnt(8)" ::: "memory");   // tile 0 landed; 1,2 in flight
  BAR();

  // ---- main loop: one barrier per K-tile, everything else free-running ----
#pragma unroll 4
  for (int t = 0; t < NT; ++t) {
    const int slot = t & 3;
    const u16* sA = lds + slot * 16384;
    const u16* sB = lds + slot * 16384 + 8192;
    u16* dst = lds + ((t + 3) & 3) * 16384;
    const bool st = (t + 3 < NT);
    const size_t koff = (size_t)(t + 3) * BK;

    // first half: A-frags m0-3 + all B-frags, stage next A, MFMA cluster 1
    s16x8 afr[4], bfr[4];
#pragma unroll
    for (int m = 0; m < 4; ++m)
      afr[m] = *reinterpret_cast<const s16x8*>(
          &sA[(wr * 128 + m * 16 + fr) * 32 + cp * 8]);
#pragma unroll
    for (int n = 0; n < 4; ++n)
      bfr[n] = *reinterpret_cast<const s16x8*>(
          &sB[(wc * 64 + n * 16 + fr) * 32 + cp * 8]);
    if (st) {
      GLDS(aS0 + koff, dst +        c0 * 512);
      GLDS(aS1 + koff, dst +        c1 * 512);
    }
    __builtin_amdgcn_s_setprio(1);
#pragma unroll
    for (int m = 0; m < 4; ++m)
#pragma unroll
      for (int n = 0; n < 4; ++n)
        acc[m][n] = __builtin_amdgcn_mfma_f32_16x16x32_bf16(
            afr[m], bfr[n], acc[m][n], 0, 0, 0);
    __builtin_amdgcn_s_setprio(0);

    // second half: A-frags m4-7, stage next B, MFMA cluster 2
    s16x8 afr2[4];
#pragma unroll
    for (int m = 0; m < 4; ++m)
      afr2[m] = *reinterpret_cast<const s16x8*>(
          &sA[(wr * 128 + (4 + m) * 16 + fr) * 32 + cp * 8]);
    if (st) {
      GLDS(bS0 + koff, dst + 8192 + c0 * 512);
      GLDS(bS1 + koff, dst + 8192 + c1 * 512);
    }
    __builtin_amdgcn_s_setprio(1);
#pragma unroll
    for (int m = 0; m < 4; ++m)
#pragma unroll
      for (int n = 0; n < 4; ++n)
        acc[4 + m][n] = __builtin_amdgcn_mfma_f32_16x16x32_bf16(
            afr2[m], bfr[n], acc[4 + m][n], 0, 0, 0);
    __builtin_amdgcn_s_setprio(0);

    // tile boundary: counted drain (never 0 mid-loop), one barrier
    if (t + 3 < NT) {
      asm volatile("s_waitcnt vmcnt(8)" ::: "memory");   // tile t+1 landed
    } else if (t + 2 < NT) {
      asm volatile("s_waitcnt vmcnt(4)" ::: "memory");
    } else if (t + 1 < NT) {
      asm volatile("s_waitcnt vmcnt(0)" ::: "memory");
    }
    if (t + 1 < NT) BAR();
  }

  // ---- epilogue: C/D layout col=lane&15, row=(lane>>4)*4 + j ----
  const int rgrp = (lane >> 4) * 4;
  if (FUSE) {
    u16* H = (u16*)Cout;
    const int ew = (bn + wc * 64) >> 6;  // wave's 64-col span = exactly one expert
#pragma unroll
    for (int m = 0; m < 8; ++m) {
#pragma unroll
      for (int j = 0; j < 4; ++j) {
        const int grow = bm + wr * 128 + m * 16 + rgrp + j;
        const float mv = mask[(size_t)grow * NEXP + ew];
#pragma unroll
        for (int n = 0; n < 4; ++n) {
          const int gcol = bn + wc * 64 + n * 16 + fr;
          float v = acc[m][n][j];
          v = v / (1.0f + __expf(-v));   // silu
          H[(size_t)grow * N + gcol] = to_bf16(v * mv);
        }
      }
    }
  } else {
    float* O = (float*)Cout;
#pragma unroll
    for (int m = 0; m < 8; ++m) {
#pragma unroll
      for (int j = 0; j < 4; ++j) {
        const int grow = bm + wr * 128 + m * 16 + rgrp + j;
#pragma unroll
        for (int n = 0; n < 4; ++n) {
          const int gcol = bn + wc * 64 + n * 16 + fr;
          O[(size_t)grow * N + gcol] = acc[m][n][j];
        }
      }
    }
  }
}

extern "C" void kernel_launch(void* const* d_in, const int* in_sizes, int n_in,
                              void* d_out, int out_size, void* d_ws, size_t ws_size,
                              hipStream_t stream) {
  const float* x     = (const float*)d_in[0];
  const float* emask = (const float*)d_in[1];
  const float* w_up  = (const float*)d_in[2];
  const float* w_dn  = (const float*)d_in[3];
  float* out = (float*)d_out;

  // workspace (bf16): x[8192,2048] | w_up[4096,2048] | w_dn[2048,4096] | H[8192,4096]
  const size_t need = ((size_t)MT * DE + (size_t)ERDIM * DE + (size_t)DE * ERDIM +
                       (size_t)MT * ERDIM) * sizeof(u16);
  if (ws_size < need) return;

  u16* xb  = (u16*)d_ws;
  u16* wub = xb  + (size_t)MT * DE;
  u16* wdb = wub + (size_t)ERDIM * DE;
  u16* hb  = wdb + (size_t)DE * ERDIM;

  hipLaunchKernelGGL(cvt_f32_bf16, dim3(2048), dim3(256), 0, stream, x,    xb,  MT * DE);
  hipLaunchKernelGGL(cvt_f32_bf16, dim3(1024), dim3(256), 0, stream, w_up, wub, ERDIM * DE);
  hipLaunchKernelGGL(cvt_f32_bf16, dim3(1024), dim3(256), 0, stream, w_dn, wdb, DE * ERDIM);

  // GEMM1: H = silu(X @ Wup^T) * mask   [M=8192, N=4096, K=2048] -> 512 blocks
  hipLaunchKernelGGL((gemm_bt<1, DE>), dim3((MT / 256) * (ERDIM / 256)), dim3(512), 0, stream,
                     xb, wub, emask, (void*)hb, MT, ERDIM);
  // GEMM2: out = H @ Wdown^T             [M=8192, N=2048, K=4096] -> 256 blocks
  hipLaunchKernelGGL((gemm_bt<0, ERDIM>), dim3((MT / 256) * (DE / 256)), dim3(512), 0, stream,
                     hb, wdb, nullptr, (void*)out, MT, DE);
}